// Round 1
// 492.513 us; speedup vs baseline: 1.0014x; 1.0014x over previous
//
#include <hip/hip_runtime.h>
#include <stdint.h>

// h1[b,o] = sum_{i,j,k} t_i a_j v_k W1[o, i*97*97 + j*97 + k], t/a/v = [1, x].
// Tile (o,i) = contiguous 9409-float W span. Inner k (k=1..96) = K=96 bf16
// MFMA GEMM vs video; k=0 / j=0 / i=0 are the prepended-ones bias terms.
//
// R3: persistent chunked blocks. Grid = 96 o x 8 i-chunks = 768 blocks
// (= 3/CU at 41 KB LDS). Each block streams its 12-13 W tiles through a
// double-buffered LDS (one barrier per tile, stage n+1 overlaps compute n),
// folds the i-dimension (x t_i) IN REGISTER.
//
// R4: kill the memset + atomics. Each (o,chunk) block now owns a private
// partial slot h1part[o][c][b] (96*8*64 fp32 = 192 KB of d_ws) written with
// one plain store per (o,b); mlp_tail folds the 8-way chunk sum into its h1
// load. Removes one dispatch (+graph gap) and the 8-deep atomic drain per
// address. Every slot has exactly one writer and all slots are written, so
// the poisoned workspace is never read stale.

#define HID    96
#define NP1    97
#define ROWLEN 9409      // 97*97 floats per (o,i) tile
#define BATCH  64
#define RSTR   104       // bf16 LDS row stride: 96 payload + 8 pad (16B-aligned rows)

typedef short bf16x8 __attribute__((ext_vector_type(8)));
typedef float f32x4  __attribute__((ext_vector_type(4)));

__device__ __forceinline__ uint32_t pack2bf(float lo, float hi) {
    union { float f; uint32_t u; } a, b; a.f = lo; b.f = hi;
    uint32_t ra = (a.u + 0x7fffu + ((a.u >> 16) & 1u)) >> 16;          // RNE lo
    uint32_t rb = (b.u + 0x7fffu + ((b.u >> 16) & 1u)) & 0xffff0000u;  // RNE hi
    return ra | rb;
}

__global__ __launch_bounds__(256, 3)
void fusion_gemm(const float* __restrict__ W1,
                 const float* __restrict__ text_x,
                 const float* __restrict__ audio_x,
                 const float* __restrict__ video_x,
                 float* __restrict__ h1part)   // [96][8][64] chunk partials
{
    __shared__ __align__(16) short Wbf[2][NP1 * RSTR];   // 2 x 20.2 KB
    __shared__ float biasF[2][NP1];                      // W[j][0] fp32

    const int tid = threadIdx.x;
    const int o   = blockIdx.x >> 3;
    const int c   = blockIdx.x & 7;
    const int ilo = (c * 97) >> 3;            // contiguous i-chunks of 12..13
    const int ihi = ((c + 1) * 97) >> 3;

    const int lane = tid & 63;
    const int wave = tid >> 6;
    const int quad = lane >> 4;
    const int col  = lane & 15;
    const int b    = wave * 16 + col;         // this lane's batch element

    // ---- hoisted: video B-fragments (K=96 = 3 k-steps of 32) ----
    // B-frag layout: lane holds B[k = quad*8+e][n = lane&15]
    bf16x8 bfrag[3];
#pragma unroll
    for (int ks = 0; ks < 3; ++ks) {
        const float* vp = video_x + b * HID + ks * 32 + quad * 8;
        union { bf16x8 v; uint32_t d[4]; } u;
        u.d[0] = pack2bf(vp[0], vp[1]);
        u.d[1] = pack2bf(vp[2], vp[3]);
        u.d[2] = pack2bf(vp[4], vp[5]);
        u.d[3] = pack2bf(vp[6], vp[7]);
        bfrag[ks] = u.v;
    }

    // ---- hoisted: audio epilogue weights for this lane's 28 j-slots ----
    // D layout: col = lane&15 -> b, row = quad*4 + reg -> j (verified R1)
    float aval[28];
#pragma unroll
    for (int mt = 0; mt < 7; ++mt)
#pragma unroll
        for (int r = 0; r < 4; ++r) {
            int j = mt * 16 + quad * 4 + r;
            aval[mt * 4 + r] = (j == 0) ? 1.f
                             : (j <= 96 ? audio_x[b * HID + (j - 1)] : 0.f);
        }

    // ---- staging helper: tile (o,ii) -> buffer pbuf, fp32->bf16 on the fly ----
    auto stage = [&](int ii, int pbuf) {
        const float* Wt = W1 + (long)(o * 97 + ii) * ROWLEN;
        for (int j = tid; j < NP1; j += 256) biasF[pbuf][j] = Wt[j * NP1];
        for (int w = tid; w < NP1 * 12; w += 256) {
            int j = w / 12;
            int s = w - j * 12;
            const float* p = Wt + j * NP1 + 1 + s * 8;   // union contiguous
            uint4 q;
            q.x = pack2bf(p[0], p[1]);
            q.y = pack2bf(p[2], p[3]);
            q.z = pack2bf(p[4], p[5]);
            q.w = pack2bf(p[6], p[7]);
            *reinterpret_cast<uint4*>(&Wbf[pbuf][j * RSTR + s * 8]) = q;  // 16B-aligned
        }
    };

    float sacc = 0.f;

    stage(ilo, 0);
    __syncthreads();

    for (int ii = ilo; ii < ihi; ++ii) {
        const int pb = (ii - ilo) & 1;
        if (ii + 1 < ihi) stage(ii + 1, pb ^ 1);   // overlaps compute below

        // ---- MFMA: U[j,b] = sum_k W[j,1+k]*video[b,k]; 7 m-tiles of 16 j ----
        f32x4 acc[7];
#pragma unroll
        for (int mt = 0; mt < 7; ++mt) acc[mt] = (f32x4){0.f, 0.f, 0.f, 0.f};
#pragma unroll
        for (int ks = 0; ks < 3; ++ks)
#pragma unroll
            for (int mt = 0; mt < 7; ++mt) {
                int j  = mt * 16 + col;            // A-frag row m
                int je = j > 96 ? 96 : j;          // clamp; garbage rows x0 below
                bf16x8 af = *reinterpret_cast<const bf16x8*>(
                    &Wbf[pb][je * RSTR + ks * 32 + quad * 8]);   // one ds_read_b128
                acc[mt] = __builtin_amdgcn_mfma_f32_16x16x32_bf16(af, bfrag[ks], acc[mt], 0, 0, 0);
            }

        // ---- epilogue: S[b] = sum_j aval_j * (U[j,b] + W[j,0]) ----
        float s = 0.f;
#pragma unroll
        for (int mt = 0; mt < 7; ++mt)
#pragma unroll
            for (int r = 0; r < 4; ++r) {
                int j  = mt * 16 + quad * 4 + r;
                int je = j > 96 ? 96 : j;
                s += (acc[mt][r] + biasF[pb][je]) * aval[mt * 4 + r];
            }
        s += __shfl_xor(s, 16);
        s += __shfl_xor(s, 32);                    // all quads: full sum over j

        float tw = (ii == 0) ? 1.f : text_x[b * HID + (ii - 1)];
        sacc += s * tw;                            // i-fold in register

        __syncthreads();                           // buf pb free for stage(ii+2)
    }

    // single writer per slot: no memset, no atomics
    if (quad == 0) h1part[(o * 8 + c) * BATCH + b] = sacc;
}

__global__ __launch_bounds__(64)
void mlp_tail(const float* __restrict__ h1part, const float* __restrict__ b1,
              const float* __restrict__ W2, const float* __restrict__ b2,
              const float* __restrict__ W3, const float* __restrict__ b3,
              float* __restrict__ out)
{
    __shared__ float h1s[96];
    __shared__ float h2s[48];
    const int b = blockIdx.x;
    const int t = threadIdx.x;
    for (int o = t; o < 96; o += 64) {
        float v = b1[o];
        const float* p = h1part + o * (8 * BATCH) + b;
#pragma unroll
        for (int c = 0; c < 8; ++c) v += p[c * BATCH];   // fold chunk partials
        h1s[o] = v > 0.f ? v : 0.f;
    }
    __syncthreads();
    if (t < 48) {
        float acc = b2[t];
#pragma unroll 8
        for (int o = 0; o < 96; ++o) acc += W2[t * 96 + o] * h1s[o];
        h2s[t] = acc > 0.f ? acc : 0.f;
    }
    __syncthreads();
    if (t < 3) {
        float acc = b3[t];
#pragma unroll
        for (int c = 0; c < 48; ++c) acc += W3[t * 48 + c] * h2s[c];
        out[b * 3 + t] = acc;
    }
}

extern "C" void kernel_launch(void* const* d_in, const int* in_sizes, int n_in,
                              void* d_out, int out_size, void* d_ws, size_t ws_size,
                              hipStream_t stream)
{
    const float* text  = (const float*)d_in[0];
    const float* audio = (const float*)d_in[1];
    const float* video = (const float*)d_in[2];
    const float* W1    = (const float*)d_in[3];
    const float* b1    = (const float*)d_in[4];
    const float* W2    = (const float*)d_in[5];
    const float* b2    = (const float*)d_in[6];
    const float* W3    = (const float*)d_in[7];
    const float* b3    = (const float*)d_in[8];
    float* h1part = (float*)d_ws;                      // 96*8*64 fp32 = 192 KB

    fusion_gemm<<<96 * 8, 256, 0, stream>>>(W1, text, audio, video, h1part);
    mlp_tail<<<BATCH, 64, 0, stream>>>(h1part, b1, W2, b2, W3, b3, (float*)d_out);
}